// Round 2
// baseline (728.747 us; speedup 1.0000x reference)
//
#include <hip/hip_runtime.h>
#include <math.h>

#define B_TOT 16384
#define DD    256
#define UU    32
#define NBR   8
#define MH    512
#define RH    256
#define KIN   288
#define NY    20

typedef unsigned short u16;
typedef __attribute__((ext_vector_type(8))) short bfx8;
typedef __attribute__((ext_vector_type(4))) short bfx4;
typedef __attribute__((ext_vector_type(4))) float fx4;

#define MFMA(a, b, c) __builtin_amdgcn_mfma_f32_16x16x32_bf16((a), (b), (c), 0, 0, 0)

// hardware RNE conversion: compiler pairs these into v_cvt_pk_bf16_f32 (m240)
__device__ __forceinline__ u16 f2bf(float f) {
  __bf16 h = (__bf16)f;
  return __builtin_bit_cast(u16, h);
}

// ---------------------------------------------------------------------------
// prep: fp32 -> bf16 weights (vectorized 8/thread), sigmoid(gates)
// ---------------------------------------------------------------------------
__global__ __launch_bounds__(256)
void skolr_prep(const float* __restrict__ W1, const float* __restrict__ W2,
                const float* __restrict__ rnnB, const float* __restrict__ Wout,
                const float* __restrict__ gates,
                u16* __restrict__ w1b, u16* __restrict__ w2b, u16* __restrict__ bb,
                u16* __restrict__ wob, float* __restrict__ sigg)
{
  int i = (blockIdx.x * 256 + threadIdx.x) * 8;
  const int E0 = NBR * MH * DD;        // 1048576
  const int E1 = E0 + NBR * RH * MH;   // 2097152
  const int E2 = E1 + NBR * RH * KIN;  // 2686976
  const int E3 = E2 + NBR * DD * RH;   // 3211264
  const int E4 = E3 + NBR * DD;        // 3213312
  if (i >= E4) return;
  if (i >= E3) {
    int off = i - E3;
    float4 a = *(const float4*)(gates + off);
    float4 b = *(const float4*)(gates + off + 4);
    float4 ra, rb;
    ra.x = 1.f/(1.f+expf(-a.x)); ra.y = 1.f/(1.f+expf(-a.y));
    ra.z = 1.f/(1.f+expf(-a.z)); ra.w = 1.f/(1.f+expf(-a.w));
    rb.x = 1.f/(1.f+expf(-b.x)); rb.y = 1.f/(1.f+expf(-b.y));
    rb.z = 1.f/(1.f+expf(-b.z)); rb.w = 1.f/(1.f+expf(-b.w));
    *(float4*)(sigg + off) = ra;
    *(float4*)(sigg + off + 4) = rb;
    return;
  }
  const float* src; u16* dst; int off;
  if (i < E0)      { src = W1;   dst = w1b; off = i; }
  else if (i < E1) { src = W2;   dst = w2b; off = i - E0; }
  else if (i < E2) { src = rnnB; dst = bb;  off = i - E1; }
  else             { src = Wout; dst = wob; off = i - E2; }
  float4 a = *(const float4*)(src + off);
  float4 b = *(const float4*)(src + off + 4);
  bfx8 v;
  v[0] = f2bf(a.x); v[1] = f2bf(a.y); v[2] = f2bf(a.z); v[3] = f2bf(a.w);
  v[4] = f2bf(b.x); v[5] = f2bf(b.y); v[6] = f2bf(b.z); v[7] = f2bf(b.w);
  *(bfx8*)(dst + off) = v;
}

// ---------------------------------------------------------------------------
// fused stages 1-4 per (64-row batch tile, branch n):
//   xT = W1 @ zg^T ; LN ; GELU ; gT = W2 @ x^T ; binT = rnnB @ [g,ut*dt]^T ;
//   zt1_partial = Wout[n] @ bin^T  -> atomicAdd into out (split-K over n)
// Wave w owns h rows {w*32..w*32+31} and {256+w*32..} so both x-pack halves
// are balanced across all 8 waves.
// ---------------------------------------------------------------------------
__global__ __launch_bounds__(512, 2)
void skolr_fused(const float* __restrict__ zt, const float* __restrict__ dtp,
                 const float* __restrict__ ut,
                 const u16* __restrict__ w1b, const float* __restrict__ b1,
                 const float* __restrict__ lng, const float* __restrict__ lnb,
                 const u16* __restrict__ w2b, const float* __restrict__ b2v,
                 const u16* __restrict__ rnnb, const u16* __restrict__ wob,
                 const float* __restrict__ sigg,
                 float* __restrict__ outp)
{
  __shared__ __align__(16) char smA[32768];
  __shared__ __align__(16) char smB[32768];
  const int tid = threadIdx.x;
  const int w  = tid >> 6;
  const int l  = tid & 63;
  const int lr = l & 15;
  const int lg = l >> 4;
  const int b0 = blockIdx.x * 64;
  const int n  = blockIdx.y;

  // ---- p0: stage zg = zt * sigmoid(gates[n]) bf16 -> smA (swizzled [64][512B])
  #pragma unroll
  for (int j = 0; j < 4; ++j) {
    int q = tid + (j << 9);
    int row = q >> 5, c = q & 31;
    const float* zp = zt + (size_t)(b0 + row) * DD + c * 8;
    const float* sp = sigg + n * DD + c * 8;
    float4 z0 = *(const float4*)zp;
    float4 z1 = *(const float4*)(zp + 4);
    float4 s0 = *(const float4*)sp;
    float4 s1 = *(const float4*)(sp + 4);
    bfx8 v;
    v[0] = f2bf(z0.x * s0.x); v[1] = f2bf(z0.y * s0.y);
    v[2] = f2bf(z0.z * s0.z); v[3] = f2bf(z0.w * s0.w);
    v[4] = f2bf(z1.x * s1.x); v[5] = f2bf(z1.y * s1.y);
    v[6] = f2bf(z1.z * s1.z); v[7] = f2bf(z1.w * s1.w);
    *(bfx8*)(smA + row * 512 + ((c ^ (row & 7)) << 4)) = v;
  }
  __syncthreads();   // (1)

  // ---- p1: xT[h][b] = W1[n] @ zg^T  (M=512 h, N=64 b, K=256)
  // h index for (w, mt): mt<2 -> w*32+mt*16 (half0) ; mt>=2 -> 256+w*32+(mt-2)*16
  fx4 acc1[4][4];
  #pragma unroll
  for (int mt = 0; mt < 4; ++mt)
    #pragma unroll
    for (int nt = 0; nt < 4; ++nt)
      acc1[mt][nt] = (fx4){0.f, 0.f, 0.f, 0.f};
  {
    const u16* w1base = w1b + (size_t)n * MH * DD;
    #pragma unroll
    for (int kk = 0; kk < 8; ++kk) {
      bfx8 bfr[4];
      #pragma unroll
      for (int nt = 0; nt < 4; ++nt) {
        int b = nt * 16 + lr;
        bfr[nt] = *(const bfx8*)(smA + b * 512 + ((((kk << 2) + lg) ^ (b & 7)) << 4));
      }
      #pragma unroll
      for (int mt = 0; mt < 4; ++mt) {
        int hrow = (mt < 2 ? (w << 5) + mt * 16 : 256 + (w << 5) + (mt - 2) * 16) + lr;
        bfx8 af = *(const bfx8*)(w1base + (size_t)hrow * DD + (kk << 5) + (lg << 3));
        #pragma unroll
        for (int nt = 0; nt < 4; ++nt)
          acc1[mt][nt] = MFMA(af, bfr[nt], acc1[mt][nt]);
      }
    }
  }
  #pragma unroll
  for (int mt = 0; mt < 4; ++mt) {
    int hb = (mt < 2 ? (w << 5) + mt * 16 : 256 + (w << 5) + (mt - 2) * 16) + (lg << 2);
    fx4 bv = *(const fx4*)(b1 + n * MH + hb);
    #pragma unroll
    for (int nt = 0; nt < 4; ++nt)
      acc1[mt][nt] += bv;
  }

  // ---- p2: LN stats over h per batch row
  {
    float* red = (float*)smB;   // [2][8][64]
    #pragma unroll
    for (int nt = 0; nt < 4; ++nt) {
      float s1 = 0.f, s2 = 0.f;
      #pragma unroll
      for (int mt = 0; mt < 4; ++mt)
        #pragma unroll
        for (int r = 0; r < 4; ++r) { float v = acc1[mt][nt][r]; s1 += v; s2 += v * v; }
      s1 += __shfl_xor(s1, 16); s1 += __shfl_xor(s1, 32);
      s2 += __shfl_xor(s2, 16); s2 += __shfl_xor(s2, 32);
      if (l < 16) { red[w * 64 + nt * 16 + l] = s1; red[512 + w * 64 + nt * 16 + l] = s2; }
    }
  }
  __syncthreads();   // (2)
  float* mstat = (float*)smA;   // zg dead
  if (tid < 64) {
    float* red = (float*)smB;
    float ms = 0.f, ss = 0.f;
    #pragma unroll
    for (int wv = 0; wv < 8; ++wv) { ms += red[wv * 64 + tid]; ss += red[512 + wv * 64 + tid]; }
    float mean = ms * (1.f / 512.f);
    float var  = ss * (1.f / 512.f) - mean * mean;
    mstat[tid]      = mean;
    mstat[64 + tid] = rsqrtf(var + 1e-5f);
  }
  __syncthreads();   // (3)

  // ---- p2.5: LN apply + exact GELU in regs
  #pragma unroll
  for (int mt = 0; mt < 4; ++mt) {
    int hb = (mt < 2 ? (w << 5) + mt * 16 : 256 + (w << 5) + (mt - 2) * 16) + (lg << 2);
    fx4 g4 = *(const fx4*)(lng + n * MH + hb);
    fx4 e4 = *(const fx4*)(lnb + n * MH + hb);
    #pragma unroll
    for (int nt = 0; nt < 4; ++nt) {
      int b = nt * 16 + lr;
      float mean = mstat[b], rstd = mstat[64 + b];
      #pragma unroll
      for (int r = 0; r < 4; ++r) {
        float v = (acc1[mt][nt][r] - mean) * rstd * g4[r] + e4[r];
        acc1[mt][nt][r] = 0.5f * v * (1.f + erff(v * 0.70710678118654752f));
      }
    }
  }

  // ---- p3a: ALL waves pack x half0 (mt 0,1) -> smB swizzled [b][h'*2]
  #pragma unroll
  for (int mt = 0; mt < 2; ++mt)
    #pragma unroll
    for (int nt = 0; nt < 4; ++nt) {
      int b = nt * 16 + lr;
      bfx4 p;
      p[0] = f2bf(acc1[mt][nt][0]); p[1] = f2bf(acc1[mt][nt][1]);
      p[2] = f2bf(acc1[mt][nt][2]); p[3] = f2bf(acc1[mt][nt][3]);
      int bytecol = ((w << 5) + mt * 16 + (lg << 2)) * 2;
      *(bfx4*)(smB + b * 512 + (((bytecol >> 4) ^ (b & 7)) << 4) + (bytecol & 15)) = p;
    }
  __syncthreads();   // (4)

  // ---- p4a: gT[r][b] partial, K = h 0..255
  const int r0 = w << 5;
  fx4 acc2[2][4];
  #pragma unroll
  for (int mt = 0; mt < 2; ++mt)
    #pragma unroll
    for (int nt = 0; nt < 4; ++nt)
      acc2[mt][nt] = (fx4){0.f, 0.f, 0.f, 0.f};
  const u16* w2base = w2b + (size_t)n * RH * MH;
  #pragma unroll
  for (int kk = 0; kk < 8; ++kk) {
    bfx8 xb[4];
    #pragma unroll
    for (int nt = 0; nt < 4; ++nt) {
      int b = nt * 16 + lr;
      xb[nt] = *(const bfx8*)(smB + b * 512 + ((((kk << 2) + lg) ^ (b & 7)) << 4));
    }
    #pragma unroll
    for (int mt = 0; mt < 2; ++mt) {
      bfx8 af = *(const bfx8*)(w2base + (size_t)(r0 + mt * 16 + lr) * MH + (kk << 5) + (lg << 3));
      #pragma unroll
      for (int nt = 0; nt < 4; ++nt)
        acc2[mt][nt] = MFMA(af, xb[nt], acc2[mt][nt]);
    }
  }
  __syncthreads();   // (5)

  // ---- p3b: pack x half1 (mt 2,3)
  #pragma unroll
  for (int mt = 2; mt < 4; ++mt)
    #pragma unroll
    for (int nt = 0; nt < 4; ++nt) {
      int b = nt * 16 + lr;
      bfx4 p;
      p[0] = f2bf(acc1[mt][nt][0]); p[1] = f2bf(acc1[mt][nt][1]);
      p[2] = f2bf(acc1[mt][nt][2]); p[3] = f2bf(acc1[mt][nt][3]);
      int bytecol = ((w << 5) + (mt - 2) * 16 + (lg << 2)) * 2;
      *(bfx4*)(smB + b * 512 + (((bytecol >> 4) ^ (b & 7)) << 4) + (bytecol & 15)) = p;
    }
  __syncthreads();   // (6)

  // ---- p4b: K = h 256..511 ; +b2 ; pack g -> smA
  #pragma unroll
  for (int kk = 8; kk < 16; ++kk) {
    bfx8 xb[4];
    #pragma unroll
    for (int nt = 0; nt < 4; ++nt) {
      int b = nt * 16 + lr;
      xb[nt] = *(const bfx8*)(smB + b * 512 + (((((kk - 8) << 2) + lg) ^ (b & 7)) << 4));
    }
    #pragma unroll
    for (int mt = 0; mt < 2; ++mt) {
      bfx8 af = *(const bfx8*)(w2base + (size_t)(r0 + mt * 16 + lr) * MH + (kk << 5) + (lg << 3));
      #pragma unroll
      for (int nt = 0; nt < 4; ++nt)
        acc2[mt][nt] = MFMA(af, xb[nt], acc2[mt][nt]);
    }
  }
  #pragma unroll
  for (int mt = 0; mt < 2; ++mt) {
    fx4 bz = *(const fx4*)(b2v + n * RH + r0 + mt * 16 + (lg << 2));
    #pragma unroll
    for (int nt = 0; nt < 4; ++nt)
      acc2[mt][nt] += bz;
  }
  #pragma unroll
  for (int mt = 0; mt < 2; ++mt)
    #pragma unroll
    for (int nt = 0; nt < 4; ++nt) {
      int b = nt * 16 + lr;
      bfx4 p;
      p[0] = f2bf(acc2[mt][nt][0]); p[1] = f2bf(acc2[mt][nt][1]);
      p[2] = f2bf(acc2[mt][nt][2]); p[3] = f2bf(acc2[mt][nt][3]);
      int bytecol = (r0 + mt * 16 + (lg << 2)) * 2;
      *(bfx4*)(smA + b * 512 + (((bytecol >> 4) ^ (b & 7)) << 4) + (bytecol & 15)) = p;
    }
  __syncthreads();   // (7)

  // ---- ut*dt B-fragments for GEMM3 k-tail
  const float dtv = dtp[0];
  bfx8 ufrag[4];
  #pragma unroll
  for (int nt = 0; nt < 4; ++nt) {
    const float* up = ut + (size_t)(b0 + nt * 16 + lr) * UU + (lg << 3);
    float4 u0 = *(const float4*)up;
    float4 u1 = *(const float4*)(up + 4);
    bfx8 v;
    v[0] = f2bf(u0.x * dtv); v[1] = f2bf(u0.y * dtv);
    v[2] = f2bf(u0.z * dtv); v[3] = f2bf(u0.w * dtv);
    v[4] = f2bf(u1.x * dtv); v[5] = f2bf(u1.y * dtv);
    v[6] = f2bf(u1.z * dtv); v[7] = f2bf(u1.w * dtv);
    ufrag[nt] = v;
  }

  // ---- p6: binT[r][b] = rnnB @ [g, ut*dt]^T  (K=288)
  fx4 acc3[2][4];
  #pragma unroll
  for (int mt = 0; mt < 2; ++mt)
    #pragma unroll
    for (int nt = 0; nt < 4; ++nt)
      acc3[mt][nt] = (fx4){0.f, 0.f, 0.f, 0.f};
  const u16* rbase = rnnb + (size_t)n * RH * KIN;
  #pragma unroll
  for (int kk = 0; kk < 8; ++kk) {
    bfx8 gb[4];
    #pragma unroll
    for (int nt = 0; nt < 4; ++nt) {
      int b = nt * 16 + lr;
      gb[nt] = *(const bfx8*)(smA + b * 512 + ((((kk << 2) + lg) ^ (b & 7)) << 4));
    }
    #pragma unroll
    for (int mt = 0; mt < 2; ++mt) {
      bfx8 af = *(const bfx8*)(rbase + (size_t)(r0 + mt * 16 + lr) * KIN + (kk << 5) + (lg << 3));
      #pragma unroll
      for (int nt = 0; nt < 4; ++nt)
        acc3[mt][nt] = MFMA(af, gb[nt], acc3[mt][nt]);
    }
  }
  #pragma unroll
  for (int mt = 0; mt < 2; ++mt) {
    bfx8 af = *(const bfx8*)(rbase + (size_t)(r0 + mt * 16 + lr) * KIN + 256 + (lg << 3));
    #pragma unroll
    for (int nt = 0; nt < 4; ++nt)
      acc3[mt][nt] = MFMA(af, ufrag[nt], acc3[mt][nt]);
  }

  // ---- pack bin -> smB (x dead)
  #pragma unroll
  for (int mt = 0; mt < 2; ++mt)
    #pragma unroll
    for (int nt = 0; nt < 4; ++nt) {
      int b = nt * 16 + lr;
      bfx4 p;
      p[0] = f2bf(acc3[mt][nt][0]); p[1] = f2bf(acc3[mt][nt][1]);
      p[2] = f2bf(acc3[mt][nt][2]); p[3] = f2bf(acc3[mt][nt][3]);
      int bytecol = (r0 + mt * 16 + (lg << 2)) * 2;
      *(bfx4*)(smB + b * 512 + (((bytecol >> 4) ^ (b & 7)) << 4) + (bytecol & 15)) = p;
    }
  __syncthreads();   // (8)

  // ---- p8: zt1T[d][b] partial = Wout[n] @ bin^T  (K=256)
  fx4 acc4[2][4];
  #pragma unroll
  for (int mt = 0; mt < 2; ++mt)
    #pragma unroll
    for (int nt = 0; nt < 4; ++nt)
      acc4[mt][nt] = (fx4){0.f, 0.f, 0.f, 0.f};
  const u16* obase = wob + (size_t)n * DD * RH;
  #pragma unroll
  for (int kk = 0; kk < 8; ++kk) {
    bfx8 bf[4];
    #pragma unroll
    for (int nt = 0; nt < 4; ++nt) {
      int b = nt * 16 + lr;
      bf[nt] = *(const bfx8*)(smB + b * 512 + ((((kk << 2) + lg) ^ (b & 7)) << 4));
    }
    #pragma unroll
    for (int mt = 0; mt < 2; ++mt) {
      bfx8 af = *(const bfx8*)(obase + (size_t)(r0 + mt * 16 + lr) * RH + (kk << 5) + (lg << 3));
      #pragma unroll
      for (int nt = 0; nt < 4; ++nt)
        acc4[mt][nt] = MFMA(af, bf[nt], acc4[mt][nt]);
    }
  }

  // ---- p9: split-K accumulate into out zt1 (device-scope atomics)
  #pragma unroll
  for (int mt = 0; mt < 2; ++mt)
    #pragma unroll
    for (int nt = 0; nt < 4; ++nt) {
      int b = b0 + nt * 16 + lr;
      int d = r0 + mt * 16 + (lg << 2);
      float* p = outp + (size_t)b * DD + d;
      atomicAdd(p + 0, acc4[mt][nt][0]);
      atomicAdd(p + 1, acc4[mt][nt][1]);
      atomicAdd(p + 2, acc4[mt][nt][2]);
      atomicAdd(p + 3, acc4[mt][nt][3]);
    }
}

// ---------------------------------------------------------------------------
// y: yt1[b][y] = dot(zt1[b], C[y]) + dt * dot(ut[b], Dm[y])
// ---------------------------------------------------------------------------
__global__ __launch_bounds__(256)
void skolr_y(const float* __restrict__ zt1, const float* __restrict__ ut,
             const float* __restrict__ dtp, const float* __restrict__ Cm,
             const float* __restrict__ Dm, float* __restrict__ yout)
{
  int t = blockIdx.x * 256 + threadIdx.x;    // exactly 16384*20 threads
  int b = t / NY;
  int y = t - b * NY;
  const float* zp = zt1 + (size_t)b * DD;
  const float* cp = Cm + y * DD;
  float s = 0.f;
  #pragma unroll 8
  for (int d = 0; d < DD; d += 4) {
    float4 z = *(const float4*)(zp + d);
    float4 c = *(const float4*)(cp + d);
    s += z.x * c.x + z.y * c.y + z.z * c.z + z.w * c.w;
  }
  const float* up = ut + (size_t)b * UU;
  const float* dp = Dm + y * UU;
  float s2 = 0.f;
  #pragma unroll
  for (int u = 0; u < UU; u += 4) {
    float4 uu = *(const float4*)(up + u);
    float4 dd = *(const float4*)(dp + u);
    s2 += uu.x * dd.x + uu.y * dd.y + uu.z * dd.z + uu.w * dd.w;
  }
  yout[t] = s + dtp[0] * s2;
}

// ---------------------------------------------------------------------------
extern "C" void kernel_launch(void* const* d_in, const int* in_sizes, int n_in,
                              void* d_out, int out_size, void* d_ws, size_t ws_size,
                              hipStream_t stream)
{
  (void)in_sizes; (void)n_in; (void)out_size; (void)ws_size;
  const float* zt    = (const float*)d_in[0];
  const float* dtp   = (const float*)d_in[1];
  const float* ut    = (const float*)d_in[2];
  const float* gates = (const float*)d_in[3];
  const float* W1    = (const float*)d_in[4];
  const float* b1    = (const float*)d_in[5];
  const float* lng   = (const float*)d_in[6];
  const float* lnb   = (const float*)d_in[7];
  const float* W2    = (const float*)d_in[8];
  const float* b2    = (const float*)d_in[9];
  // d_in[10] = lam_r, d_in[11] = lam_i : unused (h0 = 0 => lambda drops out)
  const float* rnnB  = (const float*)d_in[12];
  const float* Wout  = (const float*)d_in[13];
  const float* Cm    = (const float*)d_in[14];
  const float* Dm    = (const float*)d_in[15];
  float* outp = (float*)d_out;
  char* ws = (char*)d_ws;

  u16*   w1b  = (u16*)(ws + 0);            // 2,097,152 B
  u16*   w2b  = (u16*)(ws + 2097152);      // 2,097,152 B
  u16*   bb   = (u16*)(ws + 4194304);      // 1,179,648 B
  u16*   wob  = (u16*)(ws + 5373952);      // 1,048,576 B
  float* sigg = (float*)(ws + 6422528);    //     8,192 B

  // zero zt1 accumulation region (harness poisons d_out with 0xAA)
  hipMemsetAsync(outp, 0, (size_t)B_TOT * DD * sizeof(float), stream);

  skolr_prep<<<1569, 256, 0, stream>>>(W1, W2, rnnB, Wout, gates, w1b, w2b, bb, wob, sigg);
  skolr_fused<<<dim3(256, 8), 512, 0, stream>>>(zt, dtp, ut, w1b, b1, lng, lnb, w2b, b2,
                                                bb, wob, sigg, outp);
  skolr_y<<<1280, 256, 0, stream>>>(outp, ut, dtp, Cm, Dm, outp + (size_t)B_TOT * DD);
}

// Round 3
// 453.548 us; speedup vs baseline: 1.6068x; 1.6068x over previous
//
#include <hip/hip_runtime.h>
#include <math.h>

#define B_TOT 16384
#define DD    256
#define UU    32
#define NBR   8
#define MH    512
#define RH    256
#define KIN   288
#define NY    20

typedef unsigned short u16;
typedef __attribute__((ext_vector_type(8))) short bfx8;
typedef __attribute__((ext_vector_type(4))) short bfx4;
typedef __attribute__((ext_vector_type(4))) float fx4;

#define MFMA(a, b, c) __builtin_amdgcn_mfma_f32_16x16x32_bf16((a), (b), (c), 0, 0, 0)

__device__ __forceinline__ u16 f2bf(float f) {
  __bf16 h = (__bf16)f;
  return __builtin_bit_cast(u16, h);
}
__device__ __forceinline__ float fsigmoid(float x) {
  return __builtin_amdgcn_rcpf(1.f + __expf(-x));
}
// tanh-form GELU: 0.5v(1+tanh(0.79788456(v+0.044715v^3))) = v*p/(p+1), p=e^{2s}
// max |err| vs exact erf-GELU ~3e-4 << bf16 pack noise
__device__ __forceinline__ float fgelu(float v) {
  float t = v * v;
  float z = v * __builtin_fmaf(t, 0.07135481627f, 1.5957691216f);
  float p = __expf(z);
  return v - v * __builtin_amdgcn_rcpf(p + 1.f);
}

// ---------------------------------------------------------------------------
// prep (one pass, 8 elems/thread):
//   w1g  = bf16( W1[n][h][d] * sigmoid(gates[n][d]) )   (gating folded into W1)
//   w2b  = bf16(W2), bb = bf16(rnnB)
//   wotb = bf16(Wout) transposed to [d][n*RH+r]
//   ztb  = bf16(zt)
// ---------------------------------------------------------------------------
__global__ __launch_bounds__(256)
void skolr_prep(const float* __restrict__ W1, const float* __restrict__ W2,
                const float* __restrict__ rnnB, const float* __restrict__ Wout,
                const float* __restrict__ gates, const float* __restrict__ zt,
                u16* __restrict__ w1g, u16* __restrict__ w2b, u16* __restrict__ bb,
                u16* __restrict__ wotb, u16* __restrict__ ztb)
{
  long i = (long)(blockIdx.x * 256 + threadIdx.x) * 8;
  const long E0 = 1048576;   // W1
  const long E1 = 2097152;   // +W2
  const long E2 = 2686976;   // +rnnB
  const long E3 = 3211264;   // +Wout
  const long E4 = 7405568;   // +zt (4,194,304)
  if (i >= E4) return;
  if (i < E0) {
    int n = (int)(i >> 17), d0 = (int)(i & 255);
    const float* gp = gates + n * DD + d0;
    float4 g0 = *(const float4*)gp, g1 = *(const float4*)(gp + 4);
    float4 a = *(const float4*)(W1 + i), b = *(const float4*)(W1 + i + 4);
    bfx8 v;
    v[0] = f2bf(a.x * fsigmoid(g0.x)); v[1] = f2bf(a.y * fsigmoid(g0.y));
    v[2] = f2bf(a.z * fsigmoid(g0.z)); v[3] = f2bf(a.w * fsigmoid(g0.w));
    v[4] = f2bf(b.x * fsigmoid(g1.x)); v[5] = f2bf(b.y * fsigmoid(g1.y));
    v[6] = f2bf(b.z * fsigmoid(g1.z)); v[7] = f2bf(b.w * fsigmoid(g1.w));
    *(bfx8*)(w1g + i) = v;
    return;
  }
  const float* src; u16* dst; long off;
  if (i < E1)      { src = W2;   off = i - E0; dst = w2b + off; }
  else if (i < E2) { src = rnnB; off = i - E1; dst = bb + off; }
  else if (i < E3) {
    off = i - E2;                       // Wout[n][d][r] -> wotb[d][n*256+r]
    int n = (int)(off >> 16), rem = (int)(off & 65535);
    int d = rem >> 8, r = rem & 255;
    src = Wout; dst = wotb + (size_t)d * 2048 + n * 256 + r;
  }
  else             { src = zt;   off = i - E3; dst = ztb + off; }
  float4 a = *(const float4*)(src + off), b = *(const float4*)(src + off + 4);
  bfx8 v;
  v[0] = f2bf(a.x); v[1] = f2bf(a.y); v[2] = f2bf(a.z); v[3] = f2bf(a.w);
  v[4] = f2bf(b.x); v[5] = f2bf(b.y); v[6] = f2bf(b.z); v[7] = f2bf(b.w);
  *(bfx8*)dst = v;
}

// ---------------------------------------------------------------------------
// fused stages 1-3, per (branch n = blockIdx.x -> XCD, 64-row batch tile):
//   xT = W1' @ ztb^T ; LN ; GELU(tanh) ; gT = W2 @ x^T ; binT = rnnB @ [g,u*dt]^T
// GEMM1 B-frags read DIRECT from global ztb (L1-resident 32KB tile, 8x reuse).
// 5 barriers. LDS: smX 64KB (x full / g / bin), smR 4KB (LN partials).
// ---------------------------------------------------------------------------
__global__ __launch_bounds__(512, 2)
void skolr_fused(const u16* __restrict__ ztb, const float* __restrict__ dtp,
                 const float* __restrict__ ut,
                 const u16* __restrict__ w1g, const float* __restrict__ b1,
                 const float* __restrict__ lng, const float* __restrict__ lnb,
                 const u16* __restrict__ w2g, const float* __restrict__ b2v,
                 const u16* __restrict__ rnnb, u16* __restrict__ bing)
{
  __shared__ __align__(16) char smX[65536];
  __shared__ __align__(16) float smR[1024];
  const int tid = threadIdx.x;
  const int w  = tid >> 6;
  const int l  = tid & 63;
  const int lr = l & 15;
  const int lg = l >> 4;
  const int n  = blockIdx.x;      // branch -> XCD (linear%8 == blockIdx.x)
  const int b0 = blockIdx.y * 64;

  // ---- GEMM1: xT[h][b] = W1'[n] @ ztb^T  (M=512, N=64, K=256), no staging
  fx4 acc1[4][4];
  #pragma unroll
  for (int mt = 0; mt < 4; ++mt)
    #pragma unroll
    for (int nt = 0; nt < 4; ++nt)
      acc1[mt][nt] = (fx4){0.f, 0.f, 0.f, 0.f};
  {
    const u16* zbase  = ztb + (size_t)b0 * DD;
    const u16* w1base = w1g + (size_t)n * MH * DD;
    #pragma unroll
    for (int kk = 0; kk < 8; ++kk) {
      bfx8 bfr[4];
      #pragma unroll
      for (int nt = 0; nt < 4; ++nt)
        bfr[nt] = *(const bfx8*)(zbase + (size_t)(nt * 16 + lr) * DD + (kk << 5) + (lg << 3));
      #pragma unroll
      for (int mt = 0; mt < 4; ++mt) {
        int hrow = (mt < 2 ? (w << 5) + mt * 16 : 256 + (w << 5) + (mt - 2) * 16) + lr;
        bfx8 af = *(const bfx8*)(w1base + (size_t)hrow * DD + (kk << 5) + (lg << 3));
        #pragma unroll
        for (int nt = 0; nt < 4; ++nt)
          acc1[mt][nt] = MFMA(af, bfr[nt], acc1[mt][nt]);
      }
    }
  }
  #pragma unroll
  for (int mt = 0; mt < 4; ++mt) {
    int hb = (mt < 2 ? (w << 5) + mt * 16 : 256 + (w << 5) + (mt - 2) * 16) + (lg << 2);
    fx4 bv = *(const fx4*)(b1 + n * MH + hb);
    #pragma unroll
    for (int nt = 0; nt < 4; ++nt)
      acc1[mt][nt] += bv;
  }

  // ---- LN partials: per wave 64 h-rows summed per batch col
  #pragma unroll
  for (int nt = 0; nt < 4; ++nt) {
    float s1 = 0.f, s2 = 0.f;
    #pragma unroll
    for (int mt = 0; mt < 4; ++mt)
      #pragma unroll
      for (int r = 0; r < 4; ++r) { float v = acc1[mt][nt][r]; s1 += v; s2 += v * v; }
    s1 += __shfl_xor(s1, 16); s1 += __shfl_xor(s1, 32);
    s2 += __shfl_xor(s2, 16); s2 += __shfl_xor(s2, 32);
    if (l < 16) { smR[w * 64 + nt * 16 + l] = s1; smR[512 + w * 64 + nt * 16 + l] = s2; }
  }
  __syncthreads();   // B1

  // ---- stats (redundant per-thread, no extra barrier) + LN + GELU + pack x
  float meanv[4], rstdv[4];
  #pragma unroll
  for (int nt = 0; nt < 4; ++nt) {
    float ms = 0.f, ss = 0.f;
    #pragma unroll
    for (int wv = 0; wv < 8; ++wv) {
      ms += smR[wv * 64 + nt * 16 + lr];
      ss += smR[512 + wv * 64 + nt * 16 + lr];
    }
    float mean = ms * (1.f / 512.f);
    meanv[nt] = mean;
    rstdv[nt] = rsqrtf(ss * (1.f / 512.f) - mean * mean + 1e-5f);
  }
  #pragma unroll
  for (int mt = 0; mt < 4; ++mt) {
    int htile = (mt < 2 ? (w << 5) + mt * 16 : 256 + (w << 5) + (mt - 2) * 16);
    int hb = htile + (lg << 2);
    fx4 g4 = *(const fx4*)(lng + n * MH + hb);
    fx4 e4 = *(const fx4*)(lnb + n * MH + hb);
    #pragma unroll
    for (int nt = 0; nt < 4; ++nt) {
      #pragma unroll
      for (int r = 0; r < 4; ++r) {
        float v = (acc1[mt][nt][r] - meanv[nt]) * rstdv[nt] * g4[r] + e4[r];
        acc1[mt][nt][r] = fgelu(v);
      }
      // pack to smX [b][1024B], chunk6 = byte>>4, swizzle ^((b&7)<<3)
      int b = nt * 16 + lr;
      bfx4 p;
      p[0] = f2bf(acc1[mt][nt][0]); p[1] = f2bf(acc1[mt][nt][1]);
      p[2] = f2bf(acc1[mt][nt][2]); p[3] = f2bf(acc1[mt][nt][3]);
      int chunk6 = (htile >> 3) + (lg >> 1);
      *(bfx4*)(smX + b * 1024 + ((chunk6 ^ ((b & 7) << 3)) << 4) + ((lg & 1) << 3)) = p;
    }
  }
  __syncthreads();   // B2

  // ---- GEMM2: gT[r][b] = W2[n] @ x^T  (K=512, unsplit)
  const int r0 = w << 5;
  fx4 acc2[2][4];
  #pragma unroll
  for (int mt = 0; mt < 2; ++mt)
    #pragma unroll
    for (int nt = 0; nt < 4; ++nt)
      acc2[mt][nt] = (fx4){0.f, 0.f, 0.f, 0.f};
  {
    const u16* w2base = w2g + (size_t)n * RH * MH;
    #pragma unroll
    for (int kk = 0; kk < 16; ++kk) {
      bfx8 xb[4];
      #pragma unroll
      for (int nt = 0; nt < 4; ++nt) {
        int b = nt * 16 + lr;
        xb[nt] = *(const bfx8*)(smX + b * 1024 + ((((kk << 2) + lg) ^ ((b & 7) << 3)) << 4));
      }
      #pragma unroll
      for (int mt = 0; mt < 2; ++mt) {
        bfx8 af = *(const bfx8*)(w2base + (size_t)(r0 + mt * 16 + lr) * MH + (kk << 5) + (lg << 3));
        #pragma unroll
        for (int nt = 0; nt < 4; ++nt)
          acc2[mt][nt] = MFMA(af, xb[nt], acc2[mt][nt]);
      }
    }
  }
  #pragma unroll
  for (int mt = 0; mt < 2; ++mt) {
    fx4 bz = *(const fx4*)(b2v + n * RH + r0 + mt * 16 + (lg << 2));
    #pragma unroll
    for (int nt = 0; nt < 4; ++nt)
      acc2[mt][nt] += bz;
  }
  __syncthreads();   // B3 (all GEMM2 reads of x done)

  // ---- pack g -> smX[0:32K] ([b][512B], swizzle ^(b&7))
  #pragma unroll
  for (int mt = 0; mt < 2; ++mt)
    #pragma unroll
    for (int nt = 0; nt < 4; ++nt) {
      int b = nt * 16 + lr;
      bfx4 p;
      p[0] = f2bf(acc2[mt][nt][0]); p[1] = f2bf(acc2[mt][nt][1]);
      p[2] = f2bf(acc2[mt][nt][2]); p[3] = f2bf(acc2[mt][nt][3]);
      int chunk5 = ((r0 + mt * 16) >> 3) + (lg >> 1);
      *(bfx4*)(smX + b * 512 + ((chunk5 ^ (b & 7)) << 4) + ((lg & 1) << 3)) = p;
    }
  __syncthreads();   // B4

  // ---- ut*dt fragments (loaded late to keep GEMM1/2 register pressure low)
  const float dtv = dtp[0];
  bfx8 ufrag[4];
  #pragma unroll
  for (int nt = 0; nt < 4; ++nt) {
    const float* up = ut + (size_t)(b0 + nt * 16 + lr) * UU + (lg << 3);
    float4 u0 = *(const float4*)up;
    float4 u1 = *(const float4*)(up + 4);
    bfx8 v;
    v[0] = f2bf(u0.x * dtv); v[1] = f2bf(u0.y * dtv);
    v[2] = f2bf(u0.z * dtv); v[3] = f2bf(u0.w * dtv);
    v[4] = f2bf(u1.x * dtv); v[5] = f2bf(u1.y * dtv);
    v[6] = f2bf(u1.z * dtv); v[7] = f2bf(u1.w * dtv);
    ufrag[nt] = v;
  }

  // ---- GEMM3: binT[r][b] = rnnB @ [g, ut*dt]^T  (K=288)
  fx4 acc3[2][4];
  #pragma unroll
  for (int mt = 0; mt < 2; ++mt)
    #pragma unroll
    for (int nt = 0; nt < 4; ++nt)
      acc3[mt][nt] = (fx4){0.f, 0.f, 0.f, 0.f};
  {
    const u16* rbase = rnnb + (size_t)n * RH * KIN;
    #pragma unroll
    for (int kk = 0; kk < 8; ++kk) {
      bfx8 gb[4];
      #pragma unroll
      for (int nt = 0; nt < 4; ++nt) {
        int b = nt * 16 + lr;
        gb[nt] = *(const bfx8*)(smX + b * 512 + ((((kk << 2) + lg) ^ (b & 7)) << 4));
      }
      #pragma unroll
      for (int mt = 0; mt < 2; ++mt) {
        bfx8 af = *(const bfx8*)(rbase + (size_t)(r0 + mt * 16 + lr) * KIN + (kk << 5) + (lg << 3));
        #pragma unroll
        for (int nt = 0; nt < 4; ++nt)
          acc3[mt][nt] = MFMA(af, gb[nt], acc3[mt][nt]);
      }
    }
    #pragma unroll
    for (int mt = 0; mt < 2; ++mt) {
      bfx8 af = *(const bfx8*)(rbase + (size_t)(r0 + mt * 16 + lr) * KIN + 256 + (lg << 3));
      #pragma unroll
      for (int nt = 0; nt < 4; ++nt)
        acc3[mt][nt] = MFMA(af, ufrag[nt], acc3[mt][nt]);
    }
  }
  // pack bin -> smX[32K:64K] (disjoint from g; no barrier needed before write)
  #pragma unroll
  for (int mt = 0; mt < 2; ++mt)
    #pragma unroll
    for (int nt = 0; nt < 4; ++nt) {
      int b = nt * 16 + lr;
      bfx4 p;
      p[0] = f2bf(acc3[mt][nt][0]); p[1] = f2bf(acc3[mt][nt][1]);
      p[2] = f2bf(acc3[mt][nt][2]); p[3] = f2bf(acc3[mt][nt][3]);
      int chunk5 = ((r0 + mt * 16) >> 3) + (lg >> 1);
      *(bfx4*)(smX + 32768 + b * 512 + ((chunk5 ^ (b & 7)) << 4) + ((lg & 1) << 3)) = p;
    }
  __syncthreads();   // B5

  // ---- write bing[b][n*256+r] (512B/row contiguous, 2 rows/wave)
  {
    int c = tid & 31;
    #pragma unroll
    for (int j = 0; j < 4; ++j) {
      int row = (tid >> 5) + j * 16;
      int4 v = *(const int4*)(smX + 32768 + row * 512 + ((c ^ (row & 7)) << 4));
      *(int4*)(bing + (size_t)(b0 + row) * 2048 + n * 256 + c * 8) = v;
    }
  }
}

// ---------------------------------------------------------------------------
// final: zt1T[d][b] = Wout_all[d][k=2048] @ bin^T, direct-global frags,
// no barriers in the K-loop; yt1 fused via 16KB LDS bf16 zt1 tile.
// grid 512 x 256thr: 32 batch rows/block, 4 waves x 64 d.
// ---------------------------------------------------------------------------
__global__ __launch_bounds__(256)
void skolr_final(const u16* __restrict__ bing, const u16* __restrict__ wotb,
                 const float* __restrict__ ut, const float* __restrict__ dtp,
                 const float* __restrict__ Cm, const float* __restrict__ Dm,
                 float* __restrict__ outp)
{
  __shared__ __align__(16) char sZ[16384];
  const int tid = threadIdx.x;
  const int w  = tid >> 6;
  const int l  = tid & 63;
  const int lr = l & 15;
  const int lg = l >> 4;
  const int b0 = blockIdx.x * 32;
  const int d0 = w * 64;

  fx4 acc[4][2];
  #pragma unroll
  for (int mt = 0; mt < 4; ++mt)
    #pragma unroll
    for (int nt = 0; nt < 2; ++nt)
      acc[mt][nt] = (fx4){0.f, 0.f, 0.f, 0.f};

  #pragma unroll 4
  for (int kk = 0; kk < 64; ++kk) {
    bfx8 bf[2];
    #pragma unroll
    for (int nt = 0; nt < 2; ++nt)
      bf[nt] = *(const bfx8*)(bing + (size_t)(b0 + nt * 16 + lr) * 2048 + (kk << 5) + (lg << 3));
    #pragma unroll
    for (int mt = 0; mt < 4; ++mt) {
      bfx8 af = *(const bfx8*)(wotb + (size_t)(d0 + mt * 16 + lr) * 2048 + (kk << 5) + (lg << 3));
      #pragma unroll
      for (int nt = 0; nt < 2; ++nt)
        acc[mt][nt] = MFMA(af, bf[nt], acc[mt][nt]);
    }
  }

  // epilogue: zt1 -> global fp32 (64B segments) + bf16 LDS copy
  #pragma unroll
  for (int mt = 0; mt < 4; ++mt)
    #pragma unroll
    for (int nt = 0; nt < 2; ++nt) {
      int bl = nt * 16 + lr;
      int d  = d0 + mt * 16 + (lg << 2);
      *(fx4*)(outp + (size_t)(b0 + bl) * DD + d) = acc[mt][nt];
      bfx4 p;
      p[0] = f2bf(acc[mt][nt][0]); p[1] = f2bf(acc[mt][nt][1]);
      p[2] = f2bf(acc[mt][nt][2]); p[3] = f2bf(acc[mt][nt][3]);
      int chunk5 = (d >> 3);
      *(bfx4*)(sZ + bl * 512 + (((chunk5) ^ (bl & 7)) << 4) + (((lg & 1)) << 3)) = p;
    }
  __syncthreads();

  const float dtv = dtp[0];
  for (int i = tid; i < 32 * NY; i += 256) {
    int b = i / NY;
    int y = i - b * NY;
    float s = 0.f;
    #pragma unroll 4
    for (int dc = 0; dc < 32; ++dc) {
      bfx8 zv = *(const bfx8*)(sZ + b * 512 + ((dc ^ (b & 7)) << 4));
      const float* cp = Cm + y * DD + dc * 8;
      float4 c0 = *(const float4*)cp;
      float4 c1 = *(const float4*)(cp + 4);
      float z0 = (float)__builtin_bit_cast(__bf16, (u16)zv[0]);
      float z1 = (float)__builtin_bit_cast(__bf16, (u16)zv[1]);
      float z2 = (float)__builtin_bit_cast(__bf16, (u16)zv[2]);
      float z3 = (float)__builtin_bit_cast(__bf16, (u16)zv[3]);
      float z4 = (float)__builtin_bit_cast(__bf16, (u16)zv[4]);
      float z5 = (float)__builtin_bit_cast(__bf16, (u16)zv[5]);
      float z6 = (float)__builtin_bit_cast(__bf16, (u16)zv[6]);
      float z7 = (float)__builtin_bit_cast(__bf16, (u16)zv[7]);
      s += z0 * c0.x + z1 * c0.y + z2 * c0.z + z3 * c0.w;
      s += z4 * c1.x + z5 * c1.y + z6 * c1.z + z7 * c1.w;
    }
    const float* up = ut + (size_t)(b0 + b) * UU;
    const float* dp = Dm + y * UU;
    float s2 = 0.f;
    #pragma unroll
    for (int u = 0; u < UU; u += 4) {
      float4 uu = *(const float4*)(up + u);
      float4 dd = *(const float4*)(dp + u);
      s2 += uu.x * dd.x + uu.y * dd.y + uu.z * dd.z + uu.w * dd.w;
    }
    outp[(size_t)B_TOT * DD + (size_t)(b0 + b) * NY + y] = s + dtv * s2;
  }
}

// ---------------------------------------------------------------------------
extern "C" void kernel_launch(void* const* d_in, const int* in_sizes, int n_in,
                              void* d_out, int out_size, void* d_ws, size_t ws_size,
                              hipStream_t stream)
{
  (void)in_sizes; (void)n_in; (void)out_size; (void)ws_size;
  const float* zt    = (const float*)d_in[0];
  const float* dtp   = (const float*)d_in[1];
  const float* ut    = (const float*)d_in[2];
  const float* gates = (const float*)d_in[3];
  const float* W1    = (const float*)d_in[4];
  const float* b1    = (const float*)d_in[5];
  const float* lng   = (const float*)d_in[6];
  const float* lnb   = (const float*)d_in[7];
  const float* W2    = (const float*)d_in[8];
  const float* b2    = (const float*)d_in[9];
  // d_in[10]=lam_r, d_in[11]=lam_i unused (h0 = 0 => lambda drops out)
  const float* rnnB  = (const float*)d_in[12];
  const float* Wout  = (const float*)d_in[13];
  const float* Cm    = (const float*)d_in[14];
  const float* Dm    = (const float*)d_in[15];
  float* outp = (float*)d_out;
  char* ws = (char*)d_ws;

  u16* w1g  = (u16*)(ws + 0);           //  2,097,152 B
  u16* w2b  = (u16*)(ws + 2097152);     //  2,097,152 B
  u16* bb   = (u16*)(ws + 4194304);     //  1,179,648 B
  u16* wotb = (u16*)(ws + 5373952);     //  1,048,576 B
  u16* ztb  = (u16*)(ws + 6422528);     //  8,388,608 B
  u16* bing = (u16*)(ws + 14811136);    // 67,108,864 B  (total ~78.1 MB)

  skolr_prep<<<3616, 256, 0, stream>>>(W1, W2, rnnB, Wout, gates, zt,
                                       w1g, w2b, bb, wotb, ztb);
  // grid.x = branch -> XCD (linear%8); grid.y = batch tile
  skolr_fused<<<dim3(8, 256), 512, 0, stream>>>(ztb, dtp, ut, w1g, b1, lng, lnb,
                                                w2b, b2, bb, bing);
  skolr_final<<<512, 256, 0, stream>>>(bing, wotb, ut, dtp, Cm, Dm, outp);
}

// Round 4
// 424.671 us; speedup vs baseline: 1.7160x; 1.0680x over previous
//
#include <hip/hip_runtime.h>
#include <math.h>

#define B_TOT 16384
#define DD    256
#define UU    32
#define NBR   8
#define MH    512
#define RH    256
#define KIN   288
#define NY    20

typedef unsigned short u16;
typedef __attribute__((ext_vector_type(8))) short bfx8;
typedef __attribute__((ext_vector_type(4))) short bfx4;
typedef __attribute__((ext_vector_type(4))) float fx4;

#define MFMA(a, b, c) __builtin_amdgcn_mfma_f32_16x16x32_bf16((a), (b), (c), 0, 0, 0)

__device__ __forceinline__ u16 f2bf(float f) {
  __bf16 h = (__bf16)f;
  return __builtin_bit_cast(u16, h);
}
__device__ __forceinline__ float fsigmoid(float x) {
  return __builtin_amdgcn_rcpf(1.f + __expf(-x));
}
// tanh-form GELU (max |err| vs exact ~3e-4 << bf16 pack noise)
__device__ __forceinline__ float fgelu(float v) {
  float t = v * v;
  float z = v * __builtin_fmaf(t, 0.07135481627f, 1.5957691216f);
  float p = __expf(z);
  return v - v * __builtin_amdgcn_rcpf(p + 1.f);
}
// async global->LDS, 16B per lane; LDS dest = wave-uniform base + lane*16
__device__ __forceinline__ void gload16(const void* g, void* l) {
  __builtin_amdgcn_global_load_lds((const __attribute__((address_space(1))) unsigned int*)(g),
                                   (__attribute__((address_space(3))) unsigned int*)(l),
                                   16, 0, 0);
}

// ---------------------------------------------------------------------------
// prep: w1g = bf16(W1 * sigmoid(gates)) ; w2b/bb = bf16 ; wotb = bf16 Wout^T
// to [d][n*RH+r] ; ztb = bf16(zt)
// ---------------------------------------------------------------------------
__global__ __launch_bounds__(256)
void skolr_prep(const float* __restrict__ W1, const float* __restrict__ W2,
                const float* __restrict__ rnnB, const float* __restrict__ Wout,
                const float* __restrict__ gates, const float* __restrict__ zt,
                u16* __restrict__ w1g, u16* __restrict__ w2b, u16* __restrict__ bb,
                u16* __restrict__ wotb, u16* __restrict__ ztb)
{
  long i = (long)(blockIdx.x * 256 + threadIdx.x) * 8;
  const long E0 = 1048576;   // W1
  const long E1 = 2097152;   // +W2
  const long E2 = 2686976;   // +rnnB
  const long E3 = 3211264;   // +Wout
  const long E4 = 7405568;   // +zt
  if (i >= E4) return;
  if (i < E0) {
    int n = (int)(i >> 17), d0 = (int)(i & 255);
    const float* gp = gates + n * DD + d0;
    float4 g0 = *(const float4*)gp, g1 = *(const float4*)(gp + 4);
    float4 a = *(const float4*)(W1 + i), b = *(const float4*)(W1 + i + 4);
    bfx8 v;
    v[0] = f2bf(a.x * fsigmoid(g0.x)); v[1] = f2bf(a.y * fsigmoid(g0.y));
    v[2] = f2bf(a.z * fsigmoid(g0.z)); v[3] = f2bf(a.w * fsigmoid(g0.w));
    v[4] = f2bf(b.x * fsigmoid(g1.x)); v[5] = f2bf(b.y * fsigmoid(g1.y));
    v[6] = f2bf(b.z * fsigmoid(g1.z)); v[7] = f2bf(b.w * fsigmoid(g1.w));
    *(bfx8*)(w1g + i) = v;
    return;
  }
  const float* src; u16* dst; long off;
  if (i < E1)      { src = W2;   off = i - E0; dst = w2b + off; }
  else if (i < E2) { src = rnnB; off = i - E1; dst = bb + off; }
  else if (i < E3) {
    off = i - E2;                       // Wout[n][d][r] -> wotb[d][n*256+r]
    int n = (int)(off >> 16), rem = (int)(off & 65535);
    int d = rem >> 8, r = rem & 255;
    src = Wout; dst = wotb + (size_t)d * 2048 + n * 256 + r;
  }
  else             { src = zt;   off = i - E3; dst = ztb + off; }
  float4 a = *(const float4*)(src + off), b = *(const float4*)(src + off + 4);
  bfx8 v;
  v[0] = f2bf(a.x); v[1] = f2bf(a.y); v[2] = f2bf(a.z); v[3] = f2bf(a.w);
  v[4] = f2bf(b.x); v[5] = f2bf(b.y); v[6] = f2bf(b.z); v[7] = f2bf(b.w);
  *(bfx8*)dst = v;
}

// ---------------------------------------------------------------------------
// fused stages 1-3 per (branch n -> XCD, 64-row batch tile).
// bing is written in PHYSICAL (swizzled) chunk order: chunk c of row b holds
// logical r-chunk (c ^ (b&7)) -- final stages it linearly and reads swizzled.
// ---------------------------------------------------------------------------
__global__ __launch_bounds__(512, 2)
void skolr_fused(const u16* __restrict__ ztb, const float* __restrict__ dtp,
                 const float* __restrict__ ut,
                 const u16* __restrict__ w1g, const float* __restrict__ b1,
                 const float* __restrict__ lng, const float* __restrict__ lnb,
                 const u16* __restrict__ w2g, const float* __restrict__ b2v,
                 const u16* __restrict__ rnnb, u16* __restrict__ bing)
{
  __shared__ __align__(16) char smX[65536];
  __shared__ __align__(16) float smR[1024];
  const int tid = threadIdx.x;
  const int w  = tid >> 6;
  const int l  = tid & 63;
  const int lr = l & 15;
  const int lg = l >> 4;
  const int n  = blockIdx.x;      // branch -> XCD
  const int b0 = blockIdx.y * 64;

  // ---- GEMM1: xT[h][b] = W1'[n] @ ztb^T  (M=512, N=64, K=256)
  fx4 acc1[4][4];
  #pragma unroll
  for (int mt = 0; mt < 4; ++mt)
    #pragma unroll
    for (int nt = 0; nt < 4; ++nt)
      acc1[mt][nt] = (fx4){0.f, 0.f, 0.f, 0.f};
  {
    const u16* zbase  = ztb + (size_t)b0 * DD;
    const u16* w1base = w1g + (size_t)n * MH * DD;
    #pragma unroll
    for (int kk = 0; kk < 8; ++kk) {
      bfx8 bfr[4];
      #pragma unroll
      for (int nt = 0; nt < 4; ++nt)
        bfr[nt] = *(const bfx8*)(zbase + (size_t)(nt * 16 + lr) * DD + (kk << 5) + (lg << 3));
      #pragma unroll
      for (int mt = 0; mt < 4; ++mt) {
        int hrow = (mt < 2 ? (w << 5) + mt * 16 : 256 + (w << 5) + (mt - 2) * 16) + lr;
        bfx8 af = *(const bfx8*)(w1base + (size_t)hrow * DD + (kk << 5) + (lg << 3));
        #pragma unroll
        for (int nt = 0; nt < 4; ++nt)
          acc1[mt][nt] = MFMA(af, bfr[nt], acc1[mt][nt]);
      }
    }
  }
  #pragma unroll
  for (int mt = 0; mt < 4; ++mt) {
    int hb = (mt < 2 ? (w << 5) + mt * 16 : 256 + (w << 5) + (mt - 2) * 16) + (lg << 2);
    fx4 bv = *(const fx4*)(b1 + n * MH + hb);
    #pragma unroll
    for (int nt = 0; nt < 4; ++nt)
      acc1[mt][nt] += bv;
  }

  // ---- LN partials
  #pragma unroll
  for (int nt = 0; nt < 4; ++nt) {
    float s1 = 0.f, s2 = 0.f;
    #pragma unroll
    for (int mt = 0; mt < 4; ++mt)
      #pragma unroll
      for (int r = 0; r < 4; ++r) { float v = acc1[mt][nt][r]; s1 += v; s2 += v * v; }
    s1 += __shfl_xor(s1, 16); s1 += __shfl_xor(s1, 32);
    s2 += __shfl_xor(s2, 16); s2 += __shfl_xor(s2, 32);
    if (l < 16) { smR[w * 64 + nt * 16 + l] = s1; smR[512 + w * 64 + nt * 16 + l] = s2; }
  }
  __syncthreads();   // B1

  // ---- stats (redundant per-thread) + LN + GELU + pack x
  float meanv[4], rstdv[4];
  #pragma unroll
  for (int nt = 0; nt < 4; ++nt) {
    float ms = 0.f, ss = 0.f;
    #pragma unroll
    for (int wv = 0; wv < 8; ++wv) {
      ms += smR[wv * 64 + nt * 16 + lr];
      ss += smR[512 + wv * 64 + nt * 16 + lr];
    }
    float mean = ms * (1.f / 512.f);
    meanv[nt] = mean;
    rstdv[nt] = rsqrtf(ss * (1.f / 512.f) - mean * mean + 1e-5f);
  }
  #pragma unroll
  for (int mt = 0; mt < 4; ++mt) {
    int htile = (mt < 2 ? (w << 5) + mt * 16 : 256 + (w << 5) + (mt - 2) * 16);
    int hb = htile + (lg << 2);
    fx4 g4 = *(const fx4*)(lng + n * MH + hb);
    fx4 e4 = *(const fx4*)(lnb + n * MH + hb);
    #pragma unroll
    for (int nt = 0; nt < 4; ++nt) {
      #pragma unroll
      for (int r = 0; r < 4; ++r) {
        float v = (acc1[mt][nt][r] - meanv[nt]) * rstdv[nt] * g4[r] + e4[r];
        acc1[mt][nt][r] = fgelu(v);
      }
      // pack to smX [b][1024B]; bank-correct swizzle: XOR in chunk bits 0-2
      int b = nt * 16 + lr;
      bfx4 p;
      p[0] = f2bf(acc1[mt][nt][0]); p[1] = f2bf(acc1[mt][nt][1]);
      p[2] = f2bf(acc1[mt][nt][2]); p[3] = f2bf(acc1[mt][nt][3]);
      int chunk6 = (htile >> 3) + (lg >> 1);
      *(bfx4*)(smX + b * 1024 + ((chunk6 ^ (b & 7)) << 4) + ((lg & 1) << 3)) = p;
    }
  }
  __syncthreads();   // B2

  // ---- GEMM2: gT[r][b] = W2[n] @ x^T  (K=512)
  const int r0 = w << 5;
  fx4 acc2[2][4];
  #pragma unroll
  for (int mt = 0; mt < 2; ++mt)
    #pragma unroll
    for (int nt = 0; nt < 4; ++nt)
      acc2[mt][nt] = (fx4){0.f, 0.f, 0.f, 0.f};
  {
    const u16* w2base = w2g + (size_t)n * RH * MH;
    #pragma unroll
    for (int kk = 0; kk < 16; ++kk) {
      bfx8 xb[4];
      #pragma unroll
      for (int nt = 0; nt < 4; ++nt) {
        int b = nt * 16 + lr;
        xb[nt] = *(const bfx8*)(smX + b * 1024 + ((((kk << 2) + lg) ^ (b & 7)) << 4));
      }
      #pragma unroll
      for (int mt = 0; mt < 2; ++mt) {
        bfx8 af = *(const bfx8*)(w2base + (size_t)(r0 + mt * 16 + lr) * MH + (kk << 5) + (lg << 3));
        #pragma unroll
        for (int nt = 0; nt < 4; ++nt)
          acc2[mt][nt] = MFMA(af, xb[nt], acc2[mt][nt]);
      }
    }
  }
  #pragma unroll
  for (int mt = 0; mt < 2; ++mt) {
    fx4 bz = *(const fx4*)(b2v + n * RH + r0 + mt * 16 + (lg << 2));
    #pragma unroll
    for (int nt = 0; nt < 4; ++nt)
      acc2[mt][nt] += bz;
  }
  __syncthreads();   // B3

  // ---- pack g -> smX[0:32K] ([b][512B], ^(b&7))
  #pragma unroll
  for (int mt = 0; mt < 2; ++mt)
    #pragma unroll
    for (int nt = 0; nt < 4; ++nt) {
      int b = nt * 16 + lr;
      bfx4 p;
      p[0] = f2bf(acc2[mt][nt][0]); p[1] = f2bf(acc2[mt][nt][1]);
      p[2] = f2bf(acc2[mt][nt][2]); p[3] = f2bf(acc2[mt][nt][3]);
      int chunk5 = ((r0 + mt * 16) >> 3) + (lg >> 1);
      *(bfx4*)(smX + b * 512 + ((chunk5 ^ (b & 7)) << 4) + ((lg & 1) << 3)) = p;
    }
  __syncthreads();   // B4

  // ---- ut*dt fragments
  const float dtv = dtp[0];
  bfx8 ufrag[4];
  #pragma unroll
  for (int nt = 0; nt < 4; ++nt) {
    const float* up = ut + (size_t)(b0 + nt * 16 + lr) * UU + (lg << 3);
    float4 u0 = *(const float4*)up;
    float4 u1 = *(const float4*)(up + 4);
    bfx8 v;
    v[0] = f2bf(u0.x * dtv); v[1] = f2bf(u0.y * dtv);
    v[2] = f2bf(u0.z * dtv); v[3] = f2bf(u0.w * dtv);
    v[4] = f2bf(u1.x * dtv); v[5] = f2bf(u1.y * dtv);
    v[6] = f2bf(u1.z * dtv); v[7] = f2bf(u1.w * dtv);
    ufrag[nt] = v;
  }

  // ---- GEMM3: binT[r][b] = rnnB @ [g, ut*dt]^T  (K=288)
  fx4 acc3[2][4];
  #pragma unroll
  for (int mt = 0; mt < 2; ++mt)
    #pragma unroll
    for (int nt = 0; nt < 4; ++nt)
      acc3[mt][nt] = (fx4){0.f, 0.f, 0.f, 0.f};
  {
    const u16* rbase = rnnb + (size_t)n * RH * KIN;
    #pragma unroll
    for (int kk = 0; kk < 8; ++kk) {
      bfx8 gb[4];
      #pragma unroll
      for (int nt = 0; nt < 4; ++nt) {
        int b = nt * 16 + lr;
        gb[nt] = *(const bfx8*)(smX + b * 512 + ((((kk << 2) + lg) ^ (b & 7)) << 4));
      }
      #pragma unroll
      for (int mt = 0; mt < 2; ++mt) {
        bfx8 af = *(const bfx8*)(rbase + (size_t)(r0 + mt * 16 + lr) * KIN + (kk << 5) + (lg << 3));
        #pragma unroll
        for (int nt = 0; nt < 4; ++nt)
          acc3[mt][nt] = MFMA(af, gb[nt], acc3[mt][nt]);
      }
    }
    #pragma unroll
    for (int mt = 0; mt < 2; ++mt) {
      bfx8 af = *(const bfx8*)(rbase + (size_t)(r0 + mt * 16 + lr) * KIN + 256 + (lg << 3));
      #pragma unroll
      for (int nt = 0; nt < 4; ++nt)
        acc3[mt][nt] = MFMA(af, ufrag[nt], acc3[mt][nt]);
    }
  }
  // pack bin -> smX[32K:64K]
  #pragma unroll
  for (int mt = 0; mt < 2; ++mt)
    #pragma unroll
    for (int nt = 0; nt < 4; ++nt) {
      int b = nt * 16 + lr;
      bfx4 p;
      p[0] = f2bf(acc3[mt][nt][0]); p[1] = f2bf(acc3[mt][nt][1]);
      p[2] = f2bf(acc3[mt][nt][2]); p[3] = f2bf(acc3[mt][nt][3]);
      int chunk5 = ((r0 + mt * 16) >> 3) + (lg >> 1);
      *(bfx4*)(smX + 32768 + b * 512 + ((chunk5 ^ (b & 7)) << 4) + ((lg & 1) << 3)) = p;
    }
  __syncthreads();   // B5

  // ---- write bing in PHYSICAL chunk order (no de-swizzle)
  {
    int c = tid & 31;
    #pragma unroll
    for (int j = 0; j < 4; ++j) {
      int row = (tid >> 5) + j * 16;
      int4 v = *(const int4*)(smX + 32768 + row * 512 + (c << 4));
      *(int4*)(bing + (size_t)(b0 + row) * 2048 + n * 256 + c * 8) = v;
    }
  }
}

// ---------------------------------------------------------------------------
// final: zt1T[d][b] = wotb[d][2048] @ bin^T. 512 blocks x 512 thr, 32 batch
// rows/block, K double-buffered in LDS (global_load_lds 16B, raw barriers,
// counted vmcnt). bing arrives pre-swizzled -> linear stage + swizzled read.
// yt1 fused in epilogue.
// ---------------------------------------------------------------------------
__global__ __launch_bounds__(512, 4)
void skolr_final(const u16* __restrict__ bing, const u16* __restrict__ wotb,
                 const float* __restrict__ ut, const float* __restrict__ dtp,
                 const float* __restrict__ Cm, const float* __restrict__ Dm,
                 float* __restrict__ outp)
{
  __shared__ __align__(16) char sB[32768];   // 2 x 16KB k-slice buffers
  const int tid = threadIdx.x;
  const int w  = tid >> 6;
  const int l  = tid & 63;
  const int lr = l & 15;
  const int lg = l >> 4;
  const int b0 = blockIdx.x * 32;
  const int d0 = w << 5;

  fx4 acc[2][2];
  #pragma unroll
  for (int mt = 0; mt < 2; ++mt)
    #pragma unroll
    for (int nt = 0; nt < 2; ++nt)
      acc[mt][nt] = (fx4){0.f, 0.f, 0.f, 0.f};

  const int srow = tid >> 5;       // 0..15
  const int scol = tid & 31;       // chunk within 512B
  // stage slice ks into buffer buf: 32 rows x 512B, linear (pre-swizzled src)
  #define STAGE(buf, ks)                                                        \
    {                                                                           \
      _Pragma("unroll")                                                         \
      for (int j = 0; j < 2; ++j) {                                             \
        const u16* src = bing + (size_t)(b0 + srow + j * 16) * 2048             \
                              + ((ks) << 8) + (scol << 3);                      \
        void* ldst = sB + (buf) * 16384 + (w << 10) + (j << 13);                \
        gload16(src, ldst);                                                     \
      }                                                                         \
    }

  STAGE(0, 0)
  for (int ks = 0; ks < 8; ++ks) {
    if (ks < 7) {
      STAGE((ks + 1) & 1, ks + 1)
      asm volatile("s_waitcnt vmcnt(2)" ::: "memory");   // slice ks complete
    } else {
      asm volatile("s_waitcnt vmcnt(0)" ::: "memory");
    }
    __builtin_amdgcn_s_barrier();
    const char* cur = sB + (ks & 1) * 16384;
    #pragma unroll
    for (int kk = 0; kk < 8; ++kk) {
      bfx8 bf[2];
      #pragma unroll
      for (int nt = 0; nt < 2; ++nt) {
        int b = nt * 16 + lr;
        bf[nt] = *(const bfx8*)(cur + b * 512 + ((((kk << 2) + lg) ^ (b & 7)) << 4));
      }
      #pragma unroll
      for (int mt = 0; mt < 2; ++mt) {
        bfx8 af = *(const bfx8*)(wotb + (size_t)(d0 + mt * 16 + lr) * 2048 + (ks << 8) + (kk << 5) + (lg << 3));
        #pragma unroll
        for (int nt = 0; nt < 2; ++nt)
          acc[mt][nt] = MFMA(af, bf[nt], acc[mt][nt]);
      }
    }
    __builtin_amdgcn_s_barrier();   // all reads of cur done before re-stage
  }

  // epilogue: zt1 -> global fp32 + bf16 LDS copy for yt1 (reuse sB buf0)
  #pragma unroll
  for (int mt = 0; mt < 2; ++mt)
    #pragma unroll
    for (int nt = 0; nt < 2; ++nt) {
      int bl = nt * 16 + lr;
      int d  = d0 + mt * 16 + (lg << 2);
      *(fx4*)(outp + (size_t)(b0 + bl) * DD + d) = acc[mt][nt];
      bfx4 p;
      p[0] = f2bf(acc[mt][nt][0]); p[1] = f2bf(acc[mt][nt][1]);
      p[2] = f2bf(acc[mt][nt][2]); p[3] = f2bf(acc[mt][nt][3]);
      int chunk5 = d >> 3;
      *(bfx4*)(sB + bl * 512 + ((chunk5 ^ (bl & 7)) << 4) + ((lg & 1) << 3)) = p;
    }
  __syncthreads();

  const float dtv = dtp[0];
  for (int i = tid; i < 32 * NY; i += 512) {
    int b = i / NY;
    int y = i - b * NY;
    float s = 0.f;
    #pragma unroll 4
    for (int dc = 0; dc < 32; ++dc) {
      bfx8 zv = *(const bfx8*)(sB + b * 512 + ((dc ^ (b & 7)) << 4));
      const float* cp = Cm + y * DD + dc * 8;
      float4 c0 = *(const float4*)cp;
      float4 c1 = *(const float4*)(cp + 4);
      float z0 = (float)__builtin_bit_cast(__bf16, (u16)zv[0]);
      float z1 = (float)__builtin_bit_cast(__bf16, (u16)zv[1]);
      float z2 = (float)__builtin_bit_cast(__bf16, (u16)zv[2]);
      float z3 = (float)__builtin_bit_cast(__bf16, (u16)zv[3]);
      float z4 = (float)__builtin_bit_cast(__bf16, (u16)zv[4]);
      float z5 = (float)__builtin_bit_cast(__bf16, (u16)zv[5]);
      float z6 = (float)__builtin_bit_cast(__bf16, (u16)zv[6]);
      float z7 = (float)__builtin_bit_cast(__bf16, (u16)zv[7]);
      s += z0 * c0.x + z1 * c0.y + z2 * c0.z + z3 * c0.w;
      s += z4 * c1.x + z5 * c1.y + z6 * c1.z + z7 * c1.w;
    }
    const float* up = ut + (size_t)(b0 + b) * UU;
    const float* dp = Dm + y * UU;
    float s2 = 0.f;
    #pragma unroll
    for (int u = 0; u < UU; u += 4) {
      float4 uu = *(const float4*)(up + u);
      float4 dd = *(const float4*)(dp + u);
      s2 += uu.x * dd.x + uu.y * dd.y + uu.z * dd.z + uu.w * dd.w;
    }
    outp[(size_t)B_TOT * DD + (size_t)(b0 + b) * NY + y] = s + dtv * s2;
  }
}

// ---------------------------------------------------------------------------
extern "C" void kernel_launch(void* const* d_in, const int* in_sizes, int n_in,
                              void* d_out, int out_size, void* d_ws, size_t ws_size,
                              hipStream_t stream)
{
  (void)in_sizes; (void)n_in; (void)out_size; (void)ws_size;
  const float* zt    = (const float*)d_in[0];
  const float* dtp   = (const float*)d_in[1];
  const float* ut    = (const float*)d_in[2];
  const float* gates = (const float*)d_in[3];
  const float* W1    = (const float*)d_in[4];
  const float* b1    = (const float*)d_in[5];
  const float* lng   = (const float*)d_in[6];
  const float* lnb   = (const float*)d_in[7];
  const float* W2    = (const float*)d_in[8];
  const float* b2    = (const float*)d_in[9];
  // d_in[10]=lam_r, d_in[11]=lam_i unused (h0 = 0 => lambda drops out)
  const float* rnnB  = (const float*)d_in[12];
  const float* Wout  = (const float*)d_in[13];
  const float* Cm    = (const float*)d_in[14];
  const float* Dm    = (const float*)d_in[15];
  float* outp = (float*)d_out;
  char* ws = (char*)d_ws;

  u16* w1g  = (u16*)(ws + 0);           //  2,097,152 B
  u16* w2b  = (u16*)(ws + 2097152);     //  2,097,152 B
  u16* bb   = (u16*)(ws + 4194304);     //  1,179,648 B
  u16* wotb = (u16*)(ws + 5373952);     //  1,048,576 B
  u16* ztb  = (u16*)(ws + 6422528);     //  8,388,608 B
  u16* bing = (u16*)(ws + 14811136);    // 67,108,864 B

  skolr_prep<<<3616, 256, 0, stream>>>(W1, W2, rnnB, Wout, gates, zt,
                                       w1g, w2b, bb, wotb, ztb);
  skolr_fused<<<dim3(8, 256), 512, 0, stream>>>(ztb, dtp, ut, w1g, b1, lng, lnb,
                                                w2b, b2, bb, bing);
  skolr_final<<<512, 512, 0, stream>>>(bing, wotb, ut, dtp, Cm, Dm, outp);
}

// Round 5
// 310.731 us; speedup vs baseline: 2.3453x; 1.3667x over previous
//
#include <hip/hip_runtime.h>
#include <math.h>

#define B_TOT 16384
#define DD    256
#define UU    32
#define NBR   8
#define MH    512
#define RH    256
#define KIN   288
#define NY    20

typedef unsigned short u16;
typedef __attribute__((ext_vector_type(8))) short bfx8;
typedef __attribute__((ext_vector_type(4))) short bfx4;
typedef __attribute__((ext_vector_type(4))) float fx4;

#define MFMA(a, b, c) __builtin_amdgcn_mfma_f32_16x16x32_bf16((a), (b), (c), 0, 0, 0)

__device__ __forceinline__ u16 f2bf(float f) {
  __bf16 h = (__bf16)f;
  return __builtin_bit_cast(u16, h);
}
__device__ __forceinline__ float fsigmoid(float x) {
  return __builtin_amdgcn_rcpf(1.f + __expf(-x));
}
// tanh-form GELU (max |err| vs exact ~3e-4 << bf16 pack noise)
__device__ __forceinline__ float fgelu(float v) {
  float t = v * v;
  float z = v * __builtin_fmaf(t, 0.07135481627f, 1.5957691216f);
  float p = __expf(z);
  return v - v * __builtin_amdgcn_rcpf(p + 1.f);
}
// async global->LDS, 16B/lane; LDS dest wave-uniform base + lane*16
__device__ __forceinline__ void gload16(const void* g, void* l) {
  __builtin_amdgcn_global_load_lds((const __attribute__((address_space(1))) unsigned int*)(g),
                                   (__attribute__((address_space(3))) unsigned int*)(l),
                                   16, 0, 0);
}

// ---------------------------------------------------------------------------
// prep: all weights converted to bf16 in MFMA FRAGMENT-PACKED layout:
//   pk[((m_tile*NKT + k_tile)*64 + lane)*8], lane = (m&15) + 16*((k>>3)&3)
// so a wave's A-frag load is one contiguous 1KB. W1 gets sigmoid(gates)
// folded in; Wout is transposed to [d][n*RH+r] then packed; ztb plain bf16.
// ---------------------------------------------------------------------------
__global__ __launch_bounds__(256)
void skolr_prep(const float* __restrict__ W1, const float* __restrict__ W2,
                const float* __restrict__ rnnB, const float* __restrict__ Wout,
                const float* __restrict__ gates, const float* __restrict__ zt,
                u16* __restrict__ w1g, u16* __restrict__ w2b, u16* __restrict__ bb,
                u16* __restrict__ wotb, u16* __restrict__ ztb)
{
  long i = (long)(blockIdx.x * 256 + threadIdx.x) * 8;
  const long E0 = 1048576;   // W1
  const long E1 = 2097152;   // +W2
  const long E2 = 2686976;   // +rnnB
  const long E3 = 3211264;   // +Wout
  const long E4 = 7405568;   // +zt
  if (i >= E4) return;
  if (i < E0) {
    int n = (int)(i >> 17), h = (int)((i >> 8) & 511), d = (int)(i & 255);
    const float* gp = gates + n * DD + d;
    float4 g0 = *(const float4*)gp, g1 = *(const float4*)(gp + 4);
    float4 a = *(const float4*)(W1 + i), b = *(const float4*)(W1 + i + 4);
    bfx8 v;
    v[0] = f2bf(a.x * fsigmoid(g0.x)); v[1] = f2bf(a.y * fsigmoid(g0.y));
    v[2] = f2bf(a.z * fsigmoid(g0.z)); v[3] = f2bf(a.w * fsigmoid(g0.w));
    v[4] = f2bf(b.x * fsigmoid(g1.x)); v[5] = f2bf(b.y * fsigmoid(g1.y));
    v[6] = f2bf(b.z * fsigmoid(g1.z)); v[7] = f2bf(b.w * fsigmoid(g1.w));
    // pack: NKT=8
    u16* dst = w1g + (size_t)n * 131072
             + ((((h >> 4) << 3) + (d >> 5)) << 9) + ((h & 15) << 3) + (((d >> 3) & 3) << 7);
    *(bfx8*)dst = v;
    return;
  }
  const float* src; u16* dst; long off;
  if (i < E1) {            // W2: [n][r][k], NKT=16
    off = i - E0;
    int n = (int)(off >> 17), r = (int)((off >> 9) & 255), k = (int)(off & 511);
    src = W2 + off;
    dst = w2b + (size_t)n * 131072
        + ((((r >> 4) << 4) + (k >> 5)) << 9) + ((r & 15) << 3) + (((k >> 3) & 3) << 7);
  } else if (i < E2) {     // rnnB: [n][r][k], K=288, NKT=9
    off = i - E1;
    int o = (int)off;
    int n = o / 73728, rem = o - n * 73728;
    int r = rem / KIN, k = rem - r * KIN;
    src = rnnB + off;
    dst = bb + (size_t)n * 73728
        + (((r >> 4) * 9 + (k >> 5)) << 9) + ((r & 15) << 3) + (((k >> 3) & 3) << 7);
  } else if (i < E3) {     // Wout[n][d][r] -> A[d][k=n*256+r], NKT=64
    off = i - E2;
    int n = (int)(off >> 16), rem = (int)(off & 65535);
    int d = rem >> 8, r = rem & 255;
    src = Wout + off;
    dst = wotb + ((((d >> 4) << 6) + (n << 3) + (r >> 5)) << 9)
        + ((d & 15) << 3) + (((r >> 3) & 3) << 7);
  } else {                 // zt plain bf16
    off = i - E3;
    src = zt + off;
    dst = ztb + off;
  }
  float4 a = *(const float4*)src, b = *(const float4*)(src + 4);
  bfx8 v;
  v[0] = f2bf(a.x); v[1] = f2bf(a.y); v[2] = f2bf(a.z); v[3] = f2bf(a.w);
  v[4] = f2bf(b.x); v[5] = f2bf(b.y); v[6] = f2bf(b.z); v[7] = f2bf(b.w);
  *(bfx8*)dst = v;
}

// ---------------------------------------------------------------------------
// fused stages 1-3 per (branch n -> XCD, 64-row batch tile).
// ztb tile staged once to LDS (global_load_lds, inverse-swizzled source);
// all weight A-frags are contiguous 1KB packed loads.
// bing written in PHYSICAL (swizzled) chunk order for final's linear stage.
// ---------------------------------------------------------------------------
__global__ __launch_bounds__(512, 2)
void skolr_fused(const u16* __restrict__ ztb, const float* __restrict__ dtp,
                 const float* __restrict__ ut,
                 const u16* __restrict__ w1g, const float* __restrict__ b1,
                 const float* __restrict__ lng, const float* __restrict__ lnb,
                 const u16* __restrict__ w2g, const float* __restrict__ b2v,
                 const u16* __restrict__ rnnb, u16* __restrict__ bing)
{
  __shared__ __align__(16) char smX[65536];
  __shared__ __align__(16) float smR[1024];
  const int tid = threadIdx.x;
  const int w  = tid >> 6;
  const int l  = tid & 63;
  const int lr = l & 15;
  const int lg = l >> 4;
  const int n  = blockIdx.x;      // branch -> XCD
  const int b0 = blockIdx.y * 64;

  // ---- S0: stage ztb tile 64x512B -> smX[0:32K], swizzled via source addr
  #pragma unroll
  for (int j = 0; j < 4; ++j) {
    int q = (w << 2) + j;             // 0..31, covers rows 2q, 2q+1
    int r = (q << 1) + (l >> 5);
    const u16* src = ztb + (size_t)(b0 + r) * DD + (((l & 31) ^ (r & 7)) << 3);
    gload16(src, smX + (q << 10));
  }
  __syncthreads();   // S0 (drains gload_lds)

  // ---- GEMM1: xT[h][b] = W1'[n] @ zg^T  (M=512, N=64, K=256)
  fx4 acc1[4][4];
  #pragma unroll
  for (int mt = 0; mt < 4; ++mt)
    #pragma unroll
    for (int nt = 0; nt < 4; ++nt)
      acc1[mt][nt] = (fx4){0.f, 0.f, 0.f, 0.f};
  {
    const u16* w1pk = w1g + (size_t)n * 131072;
    #pragma unroll
    for (int kk = 0; kk < 8; ++kk) {
      bfx8 bfr[4];
      #pragma unroll
      for (int nt = 0; nt < 4; ++nt) {
        int b = nt * 16 + lr;
        bfr[nt] = *(const bfx8*)(smX + b * 512 + ((((kk << 2) + lg) ^ (b & 7)) << 4));
      }
      #pragma unroll
      for (int mt = 0; mt < 4; ++mt) {
        int mtile = (mt < 2 ? (w << 1) + mt : 16 + (w << 1) + (mt - 2));
        bfx8 af = *(const bfx8*)(w1pk + (((mtile << 3) + kk) << 9) + (l << 3));
        #pragma unroll
        for (int nt = 0; nt < 4; ++nt)
          acc1[mt][nt] = MFMA(af, bfr[nt], acc1[mt][nt]);
      }
    }
  }
  #pragma unroll
  for (int mt = 0; mt < 4; ++mt) {
    int hb = (mt < 2 ? (w << 5) + mt * 16 : 256 + (w << 5) + (mt - 2) * 16) + (lg << 2);
    fx4 bv = *(const fx4*)(b1 + n * MH + hb);
    #pragma unroll
    for (int nt = 0; nt < 4; ++nt)
      acc1[mt][nt] += bv;
  }

  // ---- LN partials
  #pragma unroll
  for (int nt = 0; nt < 4; ++nt) {
    float s1 = 0.f, s2 = 0.f;
    #pragma unroll
    for (int mt = 0; mt < 4; ++mt)
      #pragma unroll
      for (int r = 0; r < 4; ++r) { float v = acc1[mt][nt][r]; s1 += v; s2 += v * v; }
    s1 += __shfl_xor(s1, 16); s1 += __shfl_xor(s1, 32);
    s2 += __shfl_xor(s2, 16); s2 += __shfl_xor(s2, 32);
    if (l < 16) { smR[w * 64 + nt * 16 + l] = s1; smR[512 + w * 64 + nt * 16 + l] = s2; }
  }
  __syncthreads();   // B1 (also: all GEMM1 reads of ztb tile done)

  // ---- stats (redundant per-thread) + LN + GELU + pack x -> smX[0:64K]
  float meanv[4], rstdv[4];
  #pragma unroll
  for (int nt = 0; nt < 4; ++nt) {
    float ms = 0.f, ss = 0.f;
    #pragma unroll
    for (int wv = 0; wv < 8; ++wv) {
      ms += smR[wv * 64 + nt * 16 + lr];
      ss += smR[512 + wv * 64 + nt * 16 + lr];
    }
    float mean = ms * (1.f / 512.f);
    meanv[nt] = mean;
    rstdv[nt] = rsqrtf(ss * (1.f / 512.f) - mean * mean + 1e-5f);
  }
  #pragma unroll
  for (int mt = 0; mt < 4; ++mt) {
    int htile = (mt < 2 ? (w << 5) + mt * 16 : 256 + (w << 5) + (mt - 2) * 16);
    int hb = htile + (lg << 2);
    fx4 g4 = *(const fx4*)(lng + n * MH + hb);
    fx4 e4 = *(const fx4*)(lnb + n * MH + hb);
    #pragma unroll
    for (int nt = 0; nt < 4; ++nt) {
      #pragma unroll
      for (int r = 0; r < 4; ++r) {
        float v = (acc1[mt][nt][r] - meanv[nt]) * rstdv[nt] * g4[r] + e4[r];
        acc1[mt][nt][r] = fgelu(v);
      }
      int b = nt * 16 + lr;
      bfx4 p;
      p[0] = f2bf(acc1[mt][nt][0]); p[1] = f2bf(acc1[mt][nt][1]);
      p[2] = f2bf(acc1[mt][nt][2]); p[3] = f2bf(acc1[mt][nt][3]);
      int chunk6 = (htile >> 3) + (lg >> 1);
      *(bfx4*)(smX + b * 1024 + ((chunk6 ^ (b & 7)) << 4) + ((lg & 1) << 3)) = p;
    }
  }
  __syncthreads();   // B2

  // ---- GEMM2: gT[r][b] = W2[n] @ x^T  (K=512)
  const int r0 = w << 5;
  fx4 acc2[2][4];
  #pragma unroll
  for (int mt = 0; mt < 2; ++mt)
    #pragma unroll
    for (int nt = 0; nt < 4; ++nt)
      acc2[mt][nt] = (fx4){0.f, 0.f, 0.f, 0.f};
  {
    const u16* w2pk = w2g + (size_t)n * 131072;
    #pragma unroll
    for (int kk = 0; kk < 16; ++kk) {
      bfx8 xb[4];
      #pragma unroll
      for (int nt = 0; nt < 4; ++nt) {
        int b = nt * 16 + lr;
        xb[nt] = *(const bfx8*)(smX + b * 1024 + ((((kk << 2) + lg) ^ (b & 7)) << 4));
      }
      #pragma unroll
      for (int mt = 0; mt < 2; ++mt) {
        bfx8 af = *(const bfx8*)(w2pk + (((((w << 1) + mt) << 4) + kk) << 9) + (l << 3));
        #pragma unroll
        for (int nt = 0; nt < 4; ++nt)
          acc2[mt][nt] = MFMA(af, xb[nt], acc2[mt][nt]);
      }
    }
  }
  #pragma unroll
  for (int mt = 0; mt < 2; ++mt) {
    fx4 bz = *(const fx4*)(b2v + n * RH + r0 + mt * 16 + (lg << 2));
    #pragma unroll
    for (int nt = 0; nt < 4; ++nt)
      acc2[mt][nt] += bz;
  }
  __syncthreads();   // B3

  // ---- pack g -> smX[0:32K] ([b][512B], ^(b&7))
  #pragma unroll
  for (int mt = 0; mt < 2; ++mt)
    #pragma unroll
    for (int nt = 0; nt < 4; ++nt) {
      int b = nt * 16 + lr;
      bfx4 p;
      p[0] = f2bf(acc2[mt][nt][0]); p[1] = f2bf(acc2[mt][nt][1]);
      p[2] = f2bf(acc2[mt][nt][2]); p[3] = f2bf(acc2[mt][nt][3]);
      int chunk5 = ((r0 + mt * 16) >> 3) + (lg >> 1);
      *(bfx4*)(smX + b * 512 + ((chunk5 ^ (b & 7)) << 4) + ((lg & 1) << 3)) = p;
    }
  __syncthreads();   // B4

  // ---- ut*dt fragments
  const float dtv = dtp[0];
  bfx8 ufrag[4];
  #pragma unroll
  for (int nt = 0; nt < 4; ++nt) {
    const float* up = ut + (size_t)(b0 + nt * 16 + lr) * UU + (lg << 3);
    float4 u0 = *(const float4*)up;
    float4 u1 = *(const float4*)(up + 4);
    bfx8 v;
    v[0] = f2bf(u0.x * dtv); v[1] = f2bf(u0.y * dtv);
    v[2] = f2bf(u0.z * dtv); v[3] = f2bf(u0.w * dtv);
    v[4] = f2bf(u1.x * dtv); v[5] = f2bf(u1.y * dtv);
    v[6] = f2bf(u1.z * dtv); v[7] = f2bf(u1.w * dtv);
    ufrag[nt] = v;
  }

  // ---- GEMM3: binT[r][b] = rnnB @ [g, ut*dt]^T  (K=288, NKT=9)
  fx4 acc3[2][4];
  #pragma unroll
  for (int mt = 0; mt < 2; ++mt)
    #pragma unroll
    for (int nt = 0; nt < 4; ++nt)
      acc3[mt][nt] = (fx4){0.f, 0.f, 0.f, 0.f};
  {
    const u16* rpk = rnnb + (size_t)n * 73728;
    #pragma unroll
    for (int kk = 0; kk < 8; ++kk) {
      bfx8 gb[4];
      #pragma unroll
      for (int nt = 0; nt < 4; ++nt) {
        int b = nt * 16 + lr;
        gb[nt] = *(const bfx8*)(smX + b * 512 + ((((kk << 2) + lg) ^ (b & 7)) << 4));
      }
      #pragma unroll
      for (int mt = 0; mt < 2; ++mt) {
        bfx8 af = *(const bfx8*)(rpk + (((((w << 1) + mt) * 9) + kk) << 9) + (l << 3));
        #pragma unroll
        for (int nt = 0; nt < 4; ++nt)
          acc3[mt][nt] = MFMA(af, gb[nt], acc3[mt][nt]);
      }
    }
    #pragma unroll
    for (int mt = 0; mt < 2; ++mt) {
      bfx8 af = *(const bfx8*)(rpk + (((((w << 1) + mt) * 9) + 8) << 9) + (l << 3));
      #pragma unroll
      for (int nt = 0; nt < 4; ++nt)
        acc3[mt][nt] = MFMA(af, ufrag[nt], acc3[mt][nt]);
    }
  }
  // pack bin -> smX[32K:64K]
  #pragma unroll
  for (int mt = 0; mt < 2; ++mt)
    #pragma unroll
    for (int nt = 0; nt < 4; ++nt) {
      int b = nt * 16 + lr;
      bfx4 p;
      p[0] = f2bf(acc3[mt][nt][0]); p[1] = f2bf(acc3[mt][nt][1]);
      p[2] = f2bf(acc3[mt][nt][2]); p[3] = f2bf(acc3[mt][nt][3]);
      int chunk5 = ((r0 + mt * 16) >> 3) + (lg >> 1);
      *(bfx4*)(smX + 32768 + b * 512 + ((chunk5 ^ (b & 7)) << 4) + ((lg & 1) << 3)) = p;
    }
  __syncthreads();   // B5

  // ---- write bing in PHYSICAL chunk order (no de-swizzle)
  {
    int c = tid & 31;
    #pragma unroll
    for (int j = 0; j < 4; ++j) {
      int row = (tid >> 5) + j * 16;
      int4 v = *(const int4*)(smX + 32768 + row * 512 + (c << 4));
      *(int4*)(bing + (size_t)(b0 + row) * 2048 + n * 256 + c * 8) = v;
    }
  }
}

// ---------------------------------------------------------------------------
// final: zt1T[d][b] = wot_pk[d][2048] @ bin^T. 512 blocks x 512 thr, 32 batch
// rows/block. bing k-slices double-buffered in LDS (global_load_lds, raw
// barriers, counted vmcnt); af = contiguous packed 1KB streams. yt1 fused.
// ---------------------------------------------------------------------------
__global__ __launch_bounds__(512, 4)
void skolr_final(const u16* __restrict__ bing, const u16* __restrict__ wotb,
                 const float* __restrict__ ut, const float* __restrict__ dtp,
                 const float* __restrict__ Cm, const float* __restrict__ Dm,
                 float* __restrict__ outp)
{
  __shared__ __align__(16) char sB[32768];   // 2 x 16KB k-slice buffers
  const int tid = threadIdx.x;
  const int w  = tid >> 6;
  const int l  = tid & 63;
  const int lr = l & 15;
  const int lg = l >> 4;
  const int b0 = blockIdx.x * 32;
  const int d0 = w << 5;

  fx4 acc[2][2];
  #pragma unroll
  for (int mt = 0; mt < 2; ++mt)
    #pragma unroll
    for (int nt = 0; nt < 2; ++nt)
      acc[mt][nt] = (fx4){0.f, 0.f, 0.f, 0.f};

  const int srow = tid >> 5;       // 0..15
  const int scol = tid & 31;       // chunk within 512B
  #define STAGE(buf, ks)                                                        \
    {                                                                           \
      _Pragma("unroll")                                                         \
      for (int j = 0; j < 2; ++j) {                                             \
        const u16* src = bing + (size_t)(b0 + srow + j * 16) * 2048             \
                              + ((ks) << 8) + (scol << 3);                      \
        void* ldst = sB + (buf) * 16384 + (w << 10) + (j << 13);                \
        gload16(src, ldst);                                                     \
      }                                                                         \
    }

  STAGE(0, 0)
  for (int ks = 0; ks < 8; ++ks) {
    if (ks < 7) {
      STAGE((ks + 1) & 1, ks + 1)
      asm volatile("s_waitcnt vmcnt(2)" ::: "memory");   // slice ks complete
    } else {
      asm volatile("s_waitcnt vmcnt(0)" ::: "memory");
    }
    __builtin_amdgcn_s_barrier();
    const char* cur = sB + (ks & 1) * 16384;
    #pragma unroll
    for (int kk = 0; kk < 8; ++kk) {
      bfx8 bf[2];
      #pragma unroll
      for (int nt = 0; nt < 2; ++nt) {
        int b = nt * 16 + lr;
        bf[nt] = *(const bfx8*)(cur + b * 512 + ((((kk << 2) + lg) ^ (b & 7)) << 4));
      }
      #pragma unroll
      for (int mt = 0; mt < 2; ++mt) {
        bfx8 af = *(const bfx8*)(wotb + (((((w << 1) + mt) << 6) + (ks << 3) + kk) << 9) + (l << 3));
        #pragma unroll
        for (int nt = 0; nt < 2; ++nt)
          acc[mt][nt] = MFMA(af, bf[nt], acc[mt][nt]);
      }
    }
    __builtin_amdgcn_s_barrier();   // all reads of cur done before re-stage
  }

  // epilogue: zt1 -> global fp32 + bf16 LDS copy for yt1 (reuse sB buf0)
  #pragma unroll
  for (int mt = 0; mt < 2; ++mt)
    #pragma unroll
    for (int nt = 0; nt < 2; ++nt) {
      int bl = nt * 16 + lr;
      int d  = d0 + mt * 16 + (lg << 2);
      *(fx4*)(outp + (size_t)(b0 + bl) * DD + d) = acc[mt][nt];
      bfx4 p;
      p[0] = f2bf(acc[mt][nt][0]); p[1] = f2bf(acc[mt][nt][1]);
      p[2] = f2bf(acc[mt][nt][2]); p[3] = f2bf(acc[mt][nt][3]);
      int chunk5 = d >> 3;
      *(bfx4*)(sB + bl * 512 + ((chunk5 ^ (bl & 7)) << 4) + ((lg & 1) << 3)) = p;
    }
  __syncthreads();

  const float dtv = dtp[0];
  for (int i = tid; i < 32 * NY; i += 512) {
    int b = i / NY;
    int y = i - b * NY;
    float s = 0.f;
    #pragma unroll 4
    for (int dc = 0; dc < 32; ++dc) {
      bfx8 zv = *(const bfx8*)(sB + b * 512 + ((dc ^ (b & 7)) << 4));
      const float* cp = Cm + y * DD + dc * 8;
      float4 c0 = *(const float4*)cp;
      float4 c1 = *(const float4*)(cp + 4);
      float z0 = (float)__builtin_bit_cast(__bf16, (u16)zv[0]);
      float z1 = (float)__builtin_bit_cast(__bf16, (u16)zv[1]);
      float z2 = (float)__builtin_bit_cast(__bf16, (u16)zv[2]);
      float z3 = (float)__builtin_bit_cast(__bf16, (u16)zv[3]);
      float z4 = (float)__builtin_bit_cast(__bf16, (u16)zv[4]);
      float z5 = (float)__builtin_bit_cast(__bf16, (u16)zv[5]);
      float z6 = (float)__builtin_bit_cast(__bf16, (u16)zv[6]);
      float z7 = (float)__builtin_bit_cast(__bf16, (u16)zv[7]);
      s += z0 * c0.x + z1 * c0.y + z2 * c0.z + z3 * c0.w;
      s += z4 * c1.x + z5 * c1.y + z6 * c1.z + z7 * c1.w;
    }
    const float* up = ut + (size_t)(b0 + b) * UU;
    const float* dp = Dm + y * UU;
    float s2 = 0.f;
    #pragma unroll
    for (int u = 0; u < UU; u += 4) {
      float4 uu = *(const float4*)(up + u);
      float4 dd = *(const float4*)(dp + u);
      s2 += uu.x * dd.x + uu.y * dd.y + uu.z * dd.z + uu.w * dd.w;
    }
    outp[(size_t)B_TOT * DD + (size_t)(b0 + b) * NY + y] = s + dtv * s2;
  }
}

// ---------------------------------------------------------------------------
extern "C" void kernel_launch(void* const* d_in, const int* in_sizes, int n_in,
                              void* d_out, int out_size, void* d_ws, size_t ws_size,
                              hipStream_t stream)
{
  (void)in_sizes; (void)n_in; (void)out_size; (void)ws_size;
  const float* zt    = (const float*)d_in[0];
  const float* dtp   = (const float*)d_in[1];
  const float* ut    = (const float*)d_in[2];
  const float* gates = (const float*)d_in[3];
  const float* W1    = (const float*)d_in[4];
  const float* b1    = (const float*)d_in[5];
  const float* lng   = (const float*)d_in[6];
  const float* lnb   = (const float*)d_in[7];
  const float* W2    = (const float*)d_in[8];
  const float* b2    = (const float*)d_in[9];
  // d_in[10]=lam_r, d_in[11]=lam_i unused (h0 = 0 => lambda drops out)
  const float* rnnB  = (const float*)d_in[12];
  const float* Wout  = (const float*)d_in[13];
  const float* Cm    = (const float*)d_in[14];
  const float* Dm    = (const float*)d_in[15];
  float* outp = (float*)d_out;
  char* ws = (char*)d_ws;

  u16* w1g  = (u16*)(ws + 0);           //  2,097,152 B
  u16* w2b  = (u16*)(ws + 2097152);     //  2,097,152 B
  u16* bb   = (u16*)(ws + 4194304);     //  1,179,648 B
  u16* wotb = (u16*)(ws + 5373952);     //  1,048,576 B
  u16* ztb  = (u16*)(ws + 6422528);     //  8,388,608 B
  u16* bing = (u16*)(ws + 14811136);    // 67,108,864 B

  skolr_prep<<<3616, 256, 0, stream>>>(W1, W2, rnnB, Wout, gates, zt,
                                       w1g, w2b, bb, wotb, ztb);
  skolr_fused<<<dim3(8, 256), 512, 0, stream>>>(ztb, dtp, ut, w1g, b1, lng, lnb,
                                                w2b, b2, bb, bing);
  skolr_final<<<512, 512, 0, stream>>>(bing, wotb, ut, dtp, Cm, Dm, outp);
}